// Round 4
// baseline (13435.146 us; speedup 1.0000x reference)
//
#include <hip/hip_runtime.h>

// Problem constants (reference: B=8, L=1024, D=2048, H=512, OMEGA=5)
#define BB 8
#define LL 1024
#define DD 2048
#define HHH 512
#define OM 5
#define T_STEPS 1014            // L - 2*OMEGA
#define MROWS (BB * T_STEPS)    // 8112

typedef __bf16 bf16;
typedef bf16 bf16x8 __attribute__((ext_vector_type(8)));
typedef bf16 bf16x4 __attribute__((ext_vector_type(4)));
typedef float f32x4 __attribute__((ext_vector_type(4)));
typedef unsigned int u32;

__device__ __forceinline__ float sigm(float x) { return 1.0f / (1.0f + __expf(-x)); }
__device__ __forceinline__ float tanh_f(float x) { return 2.0f / (1.0f + __expf(-2.0f * x)) - 1.0f; }
__device__ __forceinline__ u32 bfbits(float x) {
    bf16 b = (bf16)x;
    unsigned short s = __builtin_bit_cast(unsigned short, b);
    return (u32)s;
}
__device__ __forceinline__ float bits2f(u32 v) {
    unsigned short s = (unsigned short)(v & 0xffffu);
    return (float)__builtin_bit_cast(bf16, s);
}
__device__ __forceinline__ bf16 bits2bf(u32 v) {
    unsigned short s = (unsigned short)(v & 0xffffu);
    return __builtin_bit_cast(bf16, s);
}

// ---------------------------------------------------------------------------
// Prep kernels
// ---------------------------------------------------------------------------

__global__ void cast_x_kernel(const float* __restrict__ x, bf16* __restrict__ xb, int n4) {
    int i = blockIdx.x * 256 + threadIdx.x;
    if (i >= n4) return;
    float4 v = ((const float4*)x)[i];
    bf16x4 w = { (bf16)v.x, (bf16)v.y, (bf16)v.z, (bf16)v.w };
    *(bf16x4*)(xb + (long)i * 4) = w;
}

// Wdb/Wda: [H][D][5], Wr: [H][D][10]  ->  B^T layouts [H][K] with k = s*D + d
__global__ void prep_convw(const float* __restrict__ Wdb, const float* __restrict__ Wda,
                           const float* __restrict__ Wr,
                           bf16* __restrict__ Bdb, bf16* __restrict__ Bda, bf16* __restrict__ Br) {
    int idx = blockIdx.x * 256 + threadIdx.x;  // h*2048 + d
    if (idx >= HHH * DD) return;
    int h = idx >> 11, d = idx & 2047;
#pragma unroll
    for (int s = 0; s < 5; ++s) {
        Bdb[(long)h * 10240 + s * DD + d] = (bf16)Wdb[(long)(h * DD + d) * 5 + s];
        Bda[(long)h * 10240 + s * DD + d] = (bf16)Wda[(long)(h * DD + d) * 5 + s];
    }
#pragma unroll
    for (int s = 0; s < 10; ++s) {
        Br[(long)h * 20480 + s * DD + d] = (bf16)Wr[(long)(h * DD + d) * 10 + s];
    }
}

// Wihc: [4096][544]; output col c = dir*2048 + j*4 + g  <- Wih_dir row (g*512+j).
// K rows: 0..511 = Wih[:, :512]; 512 = hi(w512); 513 = hi(w512) (x vts_lo);
// 514 = lo(w512) (x vts_hi); 515 = bias (x 1.0); 516..543 = 0.
__global__ void prep_wihc(const float* __restrict__ Wih_fw, const float* __restrict__ bih_fw,
                          const float* __restrict__ bhh_fw,
                          const float* __restrict__ Wih_bw, const float* __restrict__ bih_bw,
                          const float* __restrict__ bhh_bw, bf16* __restrict__ Wihc) {
    int c = blockIdx.x * 256 + threadIdx.x;
    if (c >= 4096) return;
    int dir = c >> 11;
    int jg = c & 2047;
    int j = jg >> 2, g = jg & 3;
    int row = g * 512 + j;
    const float* Wih = dir ? Wih_bw : Wih_fw;
    float bias = dir ? (bih_bw[row] + bhh_bw[row]) : (bih_fw[row] + bhh_fw[row]);
    bf16* o = Wihc + (long)c * 544;
    for (int k = 0; k < 512; ++k) o[k] = (bf16)Wih[(long)row * 513 + k];
    float w512 = Wih[(long)row * 513 + 512];
    bf16 hw = (bf16)w512;
    float lw = w512 - (float)hw;
    o[512] = hw; o[513] = hw; o[514] = (bf16)lw; o[515] = (bf16)bias;
    for (int k = 516; k < 544; ++k) o[k] = (bf16)0.0f;
}

__global__ void init_kernel(u32* __restrict__ hf, u32* __restrict__ hb, u32* __restrict__ flags) {
    int i = blockIdx.x * 256 + threadIdx.x;
    if (i < 4096) { hf[i] = 0u; hb[i] = 0u; }  // slot 0 (h_init = 0), packed bf16 pairs
    if (i < 128) flags[i] = 0u;
}

// ---------------------------------------------------------------------------
// GEMM: C[M][*] = A_win/A_plain (bf16) @ B^T rows (bf16), fp32 accumulate.
// windowed: A row (b,t) = xb + (b*LL + t + shift)*DD  (contiguous im2col-free)
// cmode 0: fp32 store; cmode 1: bf16 store. cbias: per-output-col fp32 bias.
// ---------------------------------------------------------------------------
__global__ __launch_bounds__(256, 2)
void gemm_bt(const bf16* __restrict__ A, const bf16* __restrict__ Bm, void* __restrict__ Cout,
             const float* __restrict__ cbias, int M, int K, int windowed, int shift,
             int lda, int ldc, int cmode) {
    __shared__ bf16 Ash[128 * 32];  // layout [koct][row][8]
    __shared__ bf16 Bsh[128 * 32];
    const int tid = threadIdx.x;
    const int m0 = blockIdx.x * 128;
    const int n0 = blockIdx.y * 128;

    long aoff[2], boff[2];
#pragma unroll
    for (int it = 0; it < 2; ++it) {
        int idx = it * 256 + tid;
        int r = idx & 127, koct = idx >> 7;
        int mg = m0 + r; if (mg >= M) mg = M - 1;
        long abase;
        if (windowed) {
            int b = mg / T_STEPS;
            int t = mg - b * T_STEPS;
            abase = ((long)(b * LL + t + shift)) * DD;
        } else {
            abase = (long)mg * lda;
        }
        aoff[it] = abase + koct * 8;
        boff[it] = (long)(n0 + r) * K + koct * 8;
    }

    const int wave = tid >> 6, lane = tid & 63;
    const int wr = (wave >> 1) * 64;
    const int wc = (wave & 1) * 64;
    const int q = lane >> 4, mm = lane & 15;

    f32x4 acc[4][4] = {};

    for (int k0 = 0; k0 < K; k0 += 32) {
        uint4 av[2], bv[2];
#pragma unroll
        for (int it = 0; it < 2; ++it) {
            av[it] = *(const uint4*)(A + aoff[it] + k0);
            bv[it] = *(const uint4*)(Bm + boff[it] + k0);
        }
        __syncthreads();
#pragma unroll
        for (int it = 0; it < 2; ++it) {
            int idx = it * 256 + tid;
            *(uint4*)((char*)Ash + idx * 16) = av[it];
            *(uint4*)((char*)Bsh + idx * 16) = bv[it];
        }
        __syncthreads();
        bf16x8 af[4], bfr[4];
#pragma unroll
        for (int i = 0; i < 4; ++i) {
            af[i]  = *(const bf16x8*)((char*)Ash + q * 2048 + (wr + i * 16 + mm) * 16);
            bfr[i] = *(const bf16x8*)((char*)Bsh + q * 2048 + (wc + i * 16 + mm) * 16);
        }
#pragma unroll
        for (int i = 0; i < 4; ++i)
#pragma unroll
            for (int j = 0; j < 4; ++j)
                acc[i][j] = __builtin_amdgcn_mfma_f32_16x16x32_bf16(af[i], bfr[j], acc[i][j], 0, 0, 0);
    }

#pragma unroll
    for (int i = 0; i < 4; ++i) {
        int rowb = m0 + wr + i * 16 + q * 4;
#pragma unroll
        for (int j = 0; j < 4; ++j) {
            int col = n0 + wc + j * 16 + mm;
            float bias = cbias ? cbias[col] : 0.0f;
#pragma unroll
            for (int r = 0; r < 4; ++r) {
                int gr = rowb + r;
                if (gr < M) {
                    float v = acc[i][j][r] + bias;
                    if (cmode == 0) ((float*)Cout)[(long)gr * ldc + col] = v;
                    else            ((bf16*)Cout)[(long)gr * ldc + col] = (bf16)v;
                }
            }
        }
    }
}

// ---------------------------------------------------------------------------
// vts_d[b,t] = dot(db[b,t,:], da[b,t,:]) -> joint cols 512..543 (hi/lo split + 1.0 + zeros)
// ---------------------------------------------------------------------------
__global__ void vts_kernel(const float* __restrict__ dbuf, const float* __restrict__ dabuf,
                           bf16* __restrict__ joint) {
    int gid = blockIdx.x * blockDim.x + threadIdx.x;
    int wid = gid >> 6, lane = gid & 63;
    if (wid >= MROWS) return;
    const float* p1 = dbuf + (long)wid * 512 + lane * 8;
    const float* p2 = dabuf + (long)wid * 512 + lane * 8;
    float s = 0.0f;
#pragma unroll
    for (int j = 0; j < 8; ++j) s += p1[j] * p2[j];
#pragma unroll
    for (int off = 32; off > 0; off >>= 1) s += __shfl_down(s, off);
    bf16* row = joint + (long)wid * 544;
    if (lane == 0) {
        bf16 hv = (bf16)s;
        float lo = s - (float)hv;
        row[512] = hv; row[513] = (bf16)lo; row[514] = hv; row[515] = (bf16)1.0f;
    }
    if (lane >= 4 && lane < 32) row[512 + lane] = (bf16)0.0f;  // cols 516..543
}

// ---------------------------------------------------------------------------
// Persistent LSTM: 128 blocks x 64 threads, PLAIN launch.
// Co-residency argument: this kernel runs alone (stream order) on an idle
// 256-CU GPU; 128 one-wave workgroups <= 256 CUs all become resident
// immediately (1 block/CU floor), so the flag barrier cannot deadlock.
// (hipLaunchCooperativeKernel silently no-ops in this harness — R2/R3 showed
// bit-identical absmax 0.140625 == max|ref-0.5|, i.e. the LSTM never ran.)
// dir = blk>>6 (0=fw,1=bw), each WG owns 8 hidden units; Whh A-fragments live
// in VGPRs for all 1014 steps.
// hist layout per dir (u32-packed, PERMUTED hidden axis): [T+1][16 b][256 u32],
// word widx holds units (8*(widx>>2) + (widx&3)) in lo16 and +4 in hi16.
// Equivalently position p (0..511) <-> unit (p&~7) + ((p&7)>>1) + 4*(p&1).
// The same permutation is applied to Whh columns (GEMM k-invariant) and to
// Wfc indexing in final_fc.
// ALL hist traffic uses agent-scope atomics (sc1 -> coherence point), so the
// inter-WG exchange never depends on per-XCD L2 coherence of plain stores.
// ---------------------------------------------------------------------------
__global__ __launch_bounds__(64, 1)
void lstm_kernel(const float* __restrict__ Whh_fw, const float* __restrict__ Whh_bw,
                 const float* __restrict__ gih, u32* __restrict__ hist_fw,
                 u32* __restrict__ hist_bw, u32* __restrict__ flags) {
    const int wgid = blockIdx.x;
    const int dir = wgid >> 6;
    const int w = wgid & 63;
    const int j0 = w * 8;
    const int lane = threadIdx.x;
    const float* Whh = dir ? Whh_bw : Whh_fw;
    u32* hist = dir ? hist_bw : hist_fw;
    u32* fl = flags + dir * 64;

    const int q = lane >> 4, mm = lane & 15;

    // Pre-pack A fragments: local rows rl = u*4+g (u=unit, g=gate i/f/g/o),
    // MFMA A layout: lane holds A[m=lane&15][k=(lane>>4)*8 + j].
    // Column j of k-octet (ks,q) corresponds to permuted position p=ks*32+q*8+j
    // -> Whh column (p&~7) + ((j)>>1) + 4*(j&1).
    bf16x8 afrag[2][16];
#pragma unroll
    for (int mt = 0; mt < 2; ++mt) {
        int rl = mt * 16 + mm;
        int u = rl >> 2, g = rl & 3;
        const float* wrow = Whh + ((long)(g * 512 + j0 + u)) * 512;
#pragma unroll
        for (int ks = 0; ks < 16; ++ks) {
            int base = ks * 32 + q * 8;  // 8-aligned position base
            bf16x8 f;
#pragma unroll
            for (int j = 0; j < 8; ++j) {
                int col = base + (j >> 1) + ((j & 1) << 2);
                f[j] = (bf16)wrow[col];
            }
            afrag[mt][ks] = f;
        }
    }

    float c0 = 0.0f, c1 = 0.0f;
    const int bcl = (mm < 8) ? mm : 0;  // clamp gih row for pad lanes
    for (int s = 0; s < T_STEPS; ++s) {
        const int t = dir ? (T_STEPS - 1 - s) : s;
        // B fragments from h slot s (atomic u32 loads, agent scope):
        // lane (q,mm) needs positions ks*32+q*8 .. +8 of batch mm.
        const u32* hrow = hist + (long)s * 4096 + mm * 256;
        bf16x8 bfrag[16];
#pragma unroll
        for (int ks = 0; ks < 16; ++ks) {
            int wbase = ks * 16 + q * 4;
            u32 wv[4];
#pragma unroll
            for (int i = 0; i < 4; ++i)
                wv[i] = __hip_atomic_load(hrow + wbase + i, __ATOMIC_RELAXED,
                                          __HIP_MEMORY_SCOPE_AGENT);
            bf16x8 f;
#pragma unroll
            for (int i = 0; i < 4; ++i) {
                f[2 * i]     = bits2bf(wv[i]);
                f[2 * i + 1] = bits2bf(wv[i] >> 16);
            }
            bfrag[ks] = f;
        }

        // C operand = precomputed input gates (already bias-included, (j*4+g) order)
        const float* gp = gih + ((long)(bcl * T_STEPS + t)) * 4096 + dir * 2048 + (j0 + q) * 4;
        f32x4 acc0 = *(const f32x4*)gp;
        f32x4 acc1 = *(const f32x4*)(gp + 16);
#pragma unroll
        for (int ks = 0; ks < 16; ++ks) {
            acc0 = __builtin_amdgcn_mfma_f32_16x16x32_bf16(afrag[0][ks], bfrag[ks], acc0, 0, 0, 0);
            acc1 = __builtin_amdgcn_mfma_f32_16x16x32_bf16(afrag[1][ks], bfrag[ks], acc1, 0, 0, 0);
        }
        // D layout: col=lane&15=b, row=(lane>>4)*4+reg -> unit q (+4), gate = reg
        float ig = sigm(acc0[0]), fg = sigm(acc0[1]), gg = tanh_f(acc0[2]), og = sigm(acc0[3]);
        c0 = fg * c0 + ig * gg;
        float h0 = og * tanh_f(c0);
        ig = sigm(acc1[0]); fg = sigm(acc1[1]); gg = tanh_f(acc1[2]); og = sigm(acc1[3]);
        c1 = fg * c1 + ig * gg;
        float h1 = og * tanh_f(c1);

        bool valid = (mm < 8);
        u32 pw = valid ? (bfbits(h0) | (bfbits(h1) << 16)) : 0u;
        __hip_atomic_store(hist + (long)(s + 1) * 4096 + mm * 256 + (j0 >> 1) + q, pw,
                           __ATOMIC_RELAXED, __HIP_MEMORY_SCOPE_AGENT);

        // distributed-flag barrier among the 64 WGs of this direction
        __threadfence();
        if (lane == 0)
            __hip_atomic_store(&fl[w], (u32)(s + 1), __ATOMIC_RELEASE, __HIP_MEMORY_SCOPE_AGENT);
        const u32 tgt = (u32)(s + 1);
        while (true) {
            u32 v = __hip_atomic_load(&fl[lane], __ATOMIC_ACQUIRE, __HIP_MEMORY_SCOPE_AGENT);
            if (__all((int)(v >= tgt))) break;
        }
        __threadfence();
    }
}

// ---------------------------------------------------------------------------
// out[b*T+t] = sigmoid(h_fw[t] . Wfc[:512] + h_bw[t] . Wfc[512:] + bfc)
// hist is u32-packed with the permuted hidden axis: lane reads words
// lane*4 .. +4: word i -> units 8*lane+i (lo16) and 8*lane+4+i (hi16).
// ---------------------------------------------------------------------------
__global__ void final_fc(const u32* __restrict__ hist_fw, const u32* __restrict__ hist_bw,
                         const float* __restrict__ Wfc, const float* __restrict__ bfc,
                         float* __restrict__ out) {
    int gid = blockIdx.x * blockDim.x + threadIdx.x;
    int wid = gid >> 6, lane = gid & 63;
    if (wid >= MROWS) return;
    int b = wid / T_STEPS, t = wid - b * T_STEPS;
    const u32* hf = hist_fw + (long)(t + 1) * 4096 + b * 256 + lane * 4;
    const u32* hb = hist_bw + (long)(T_STEPS - t) * 4096 + b * 256 + lane * 4;
    float s = 0.0f;
#pragma unroll
    for (int i = 0; i < 4; ++i) {
        u32 wf = hf[i], wb = hb[i];
        s += bits2f(wf) * Wfc[8 * lane + i] + bits2f(wf >> 16) * Wfc[8 * lane + 4 + i];
        s += bits2f(wb) * Wfc[512 + 8 * lane + i] + bits2f(wb >> 16) * Wfc[512 + 8 * lane + 4 + i];
    }
#pragma unroll
    for (int off = 32; off > 0; off >>= 1) s += __shfl_down(s, off);
    if (lane == 0) out[wid] = 1.0f / (1.0f + __expf(-(s + bfc[0])));
}

// ---------------------------------------------------------------------------

extern "C" void kernel_launch(void* const* d_in, const int* in_sizes, int n_in,
                              void* d_out, int out_size, void* d_ws, size_t ws_size,
                              hipStream_t stream) {
    const float* x      = (const float*)d_in[0];
    const float* Wdb    = (const float*)d_in[1];
    const float* bdb    = (const float*)d_in[2];
    const float* Wda    = (const float*)d_in[3];
    const float* bda    = (const float*)d_in[4];
    const float* Wr     = (const float*)d_in[5];
    const float* br     = (const float*)d_in[6];
    const float* Wih_fw = (const float*)d_in[7];
    const float* Whh_fw = (const float*)d_in[8];
    const float* bih_fw = (const float*)d_in[9];
    const float* bhh_fw = (const float*)d_in[10];
    const float* Wih_bw = (const float*)d_in[11];
    const float* Whh_bw = (const float*)d_in[12];
    const float* bih_bw = (const float*)d_in[13];
    const float* bhh_bw = (const float*)d_in[14];
    const float* Wfc    = (const float*)d_in[15];
    const float* bfc    = (const float*)d_in[16];
    float* out = (float*)d_out;

    // ---- workspace layout with aliasing (peak ~179.5 MB) ----
    char* p = (char*)d_ws;
    auto alloc = [&](size_t bytes) { char* r = p; p += (bytes + 255) & ~(size_t)255; return r; };
    // persistent region (~46.6 MB): alive until the end
    bf16* Wihc    = (bf16*)alloc((size_t)4096 * 544 * 2);            // 4.5 MB
    bf16* joint   = (bf16*)alloc((size_t)MROWS * 544 * 2);           // 8.8 MB
    u32* hist_fw  = (u32*)alloc((size_t)(T_STEPS + 1) * 4096 * 4);   // 16.6 MB
    u32* hist_bw  = (u32*)alloc((size_t)(T_STEPS + 1) * 4096 * 4);   // 16.6 MB
    u32* flags    = (u32*)alloc(512);
    // overlay region Q: phase-1 conv buffers, later overwritten by gih
    char* q0 = p;
    bf16* xb      = (bf16*)alloc((size_t)BB * LL * DD * 2);          // 33.6 MB
    bf16* Bdb     = (bf16*)alloc((size_t)512 * 10240 * 2);           // 10.5 MB
    bf16* Bda     = (bf16*)alloc((size_t)512 * 10240 * 2);           // 10.5 MB
    bf16* Br      = (bf16*)alloc((size_t)512 * 20480 * 2);           // 21.0 MB
    float* dbuf   = (float*)alloc((size_t)MROWS * 512 * 4);          // 16.6 MB
    float* dabuf  = (float*)alloc((size_t)MROWS * 512 * 4);          // 16.6 MB
    float* gih    = (float*)q0;  // 132.9 MB, overwrites all of the above
    (void)ws_size;

    cast_x_kernel<<<16384, 256, 0, stream>>>(x, xb, BB * LL * DD / 4);
    prep_convw<<<4096, 256, 0, stream>>>(Wdb, Wda, Wr, Bdb, Bda, Br);
    prep_wihc<<<16, 256, 0, stream>>>(Wih_fw, bih_fw, bhh_fw, Wih_bw, bih_bw, bhh_bw, Wihc);
    init_kernel<<<16, 256, 0, stream>>>(hist_fw, hist_bw, flags);

    dim3 g1(64, 4);
    // db: window [t, t+5);  da: window [t+5, t+10);  r: window [t, t+10)
    gemm_bt<<<g1, 256, 0, stream>>>(xb, Bdb, dbuf, bdb, MROWS, 10240, 1, 0, 0, 512, 0);
    gemm_bt<<<g1, 256, 0, stream>>>(xb, Bda, dabuf, bda, MROWS, 10240, 1, 5, 0, 512, 0);
    gemm_bt<<<g1, 256, 0, stream>>>(xb, Br, joint, br, MROWS, 20480, 1, 0, 0, 544, 1);
    vts_kernel<<<(MROWS * 64 + 255) / 256, 256, 0, stream>>>(dbuf, dabuf, joint);

    // gih GEMM: reads only joint + Wihc; writes gih over the dead conv buffers
    dim3 g2(64, 32);
    gemm_bt<<<g2, 256, 0, stream>>>(joint, Wihc, gih, nullptr, MROWS, 544, 0, 0, 544, 4096, 0);

    // PLAIN launch (cooperative launch silently no-ops in this harness).
    // 128 blocks x 1 wave on an otherwise-idle 256-CU GPU => all co-resident.
    lstm_kernel<<<dim3(128), dim3(64), 0, stream>>>(Whh_fw, Whh_bw, gih,
                                                    hist_fw, hist_bw, flags);

    final_fc<<<(MROWS * 64 + 255) / 256, 256, 0, stream>>>(hist_fw, hist_bw, Wfc, bfc, out);
}

// Round 5
// 8088.303 us; speedup vs baseline: 1.6611x; 1.6611x over previous
//
#include <hip/hip_runtime.h>

// Problem constants (reference: B=8, L=1024, D=2048, H=512, OMEGA=5)
#define BB 8
#define LL 1024
#define DD 2048
#define HHH 512
#define OM 5
#define T_STEPS 1014            // L - 2*OMEGA
#define MROWS (BB * T_STEPS)    // 8112

typedef __bf16 bf16;
typedef bf16 bf16x8 __attribute__((ext_vector_type(8)));
typedef bf16 bf16x4 __attribute__((ext_vector_type(4)));
typedef float f32x4 __attribute__((ext_vector_type(4)));
typedef unsigned int u32;

__device__ __forceinline__ float sigm(float x) { return 1.0f / (1.0f + __expf(-x)); }
__device__ __forceinline__ float tanh_f(float x) { return 2.0f / (1.0f + __expf(-2.0f * x)) - 1.0f; }
__device__ __forceinline__ u32 bfbits(float x) {
    bf16 b = (bf16)x;
    unsigned short s = __builtin_bit_cast(unsigned short, b);
    return (u32)s;
}
__device__ __forceinline__ float bits2f(u32 v) {
    unsigned short s = (unsigned short)(v & 0xffffu);
    return (float)__builtin_bit_cast(bf16, s);
}
__device__ __forceinline__ bf16 bits2bf(u32 v) {
    unsigned short s = (unsigned short)(v & 0xffffu);
    return __builtin_bit_cast(bf16, s);
}

// ---------------------------------------------------------------------------
// Prep kernels
// ---------------------------------------------------------------------------

__global__ void cast_x_kernel(const float* __restrict__ x, bf16* __restrict__ xb, int n4) {
    int i = blockIdx.x * 256 + threadIdx.x;
    if (i >= n4) return;
    float4 v = ((const float4*)x)[i];
    bf16x4 w = { (bf16)v.x, (bf16)v.y, (bf16)v.z, (bf16)v.w };
    *(bf16x4*)(xb + (long)i * 4) = w;
}

// Wdb/Wda: [H][D][5], Wr: [H][D][10]  ->  B^T layouts [H][K] with k = s*D + d
__global__ void prep_convw(const float* __restrict__ Wdb, const float* __restrict__ Wda,
                           const float* __restrict__ Wr,
                           bf16* __restrict__ Bdb, bf16* __restrict__ Bda, bf16* __restrict__ Br) {
    int idx = blockIdx.x * 256 + threadIdx.x;  // h*2048 + d
    if (idx >= HHH * DD) return;
    int h = idx >> 11, d = idx & 2047;
#pragma unroll
    for (int s = 0; s < 5; ++s) {
        Bdb[(long)h * 10240 + s * DD + d] = (bf16)Wdb[(long)(h * DD + d) * 5 + s];
        Bda[(long)h * 10240 + s * DD + d] = (bf16)Wda[(long)(h * DD + d) * 5 + s];
    }
#pragma unroll
    for (int s = 0; s < 10; ++s) {
        Br[(long)h * 20480 + s * DD + d] = (bf16)Wr[(long)(h * DD + d) * 10 + s];
    }
}

// Wihc: [4096][544]; output col c = dir*2048 + j*4 + g  <- Wih_dir row (g*512+j).
// K rows: 0..511 = Wih[:, :512]; 512 = hi(w512); 513 = hi(w512) (x vts_lo);
// 514 = lo(w512) (x vts_hi); 515 = bias (x 1.0); 516..543 = 0.
// One block per output column c; 256 threads stride the K rows.
__global__ void prep_wihc(const float* __restrict__ Wih_fw, const float* __restrict__ bih_fw,
                          const float* __restrict__ bhh_fw,
                          const float* __restrict__ Wih_bw, const float* __restrict__ bih_bw,
                          const float* __restrict__ bhh_bw, bf16* __restrict__ Wihc) {
    int c = blockIdx.x;
    int tid = threadIdx.x;
    int dir = c >> 11;
    int jg = c & 2047;
    int j = jg >> 2, g = jg & 3;
    int row = g * 512 + j;
    const float* Wih = dir ? Wih_bw : Wih_fw;
    bf16* o = Wihc + (long)c * 544;
    for (int k = tid; k < 512; k += 256) o[k] = (bf16)Wih[(long)row * 513 + k];
    if (tid == 0) {
        float bias = dir ? (bih_bw[row] + bhh_bw[row]) : (bih_fw[row] + bhh_fw[row]);
        float w512 = Wih[(long)row * 513 + 512];
        bf16 hw = (bf16)w512;
        float lw = w512 - (float)hw;
        o[512] = hw; o[513] = hw; o[514] = (bf16)lw; o[515] = (bf16)bias;
    }
    if (tid >= 4 && tid < 32) o[512 + tid] = (bf16)0.0f;  // cols 516..543
}

__global__ void init_kernel(u32* __restrict__ hf, u32* __restrict__ hb, u32* __restrict__ flags) {
    int i = blockIdx.x * 256 + threadIdx.x;
    if (i < 4096) { hf[i] = 0u; hb[i] = 0u; }  // slot 0 (h_init = 0), packed bf16 pairs
    if (i < 128) flags[i] = 0u;
}

// ---------------------------------------------------------------------------
// GEMM: C[M][*] = A_win/A_plain (bf16) @ B^T rows (bf16), fp32 accumulate.
// windowed: A row (b,t) = xb + (b*LL + t + shift)*DD  (contiguous im2col-free)
// cmode 0: fp32 store; cmode 1: bf16 store. cbias: per-output-col fp32 bias.
// ---------------------------------------------------------------------------
__global__ __launch_bounds__(256, 2)
void gemm_bt(const bf16* __restrict__ A, const bf16* __restrict__ Bm, void* __restrict__ Cout,
             const float* __restrict__ cbias, int M, int K, int windowed, int shift,
             int lda, int ldc, int cmode) {
    __shared__ bf16 Ash[128 * 32];  // layout [koct][row][8]
    __shared__ bf16 Bsh[128 * 32];
    const int tid = threadIdx.x;
    const int m0 = blockIdx.x * 128;
    const int n0 = blockIdx.y * 128;

    long aoff[2], boff[2];
#pragma unroll
    for (int it = 0; it < 2; ++it) {
        int idx = it * 256 + tid;
        int r = idx & 127, koct = idx >> 7;
        int mg = m0 + r; if (mg >= M) mg = M - 1;
        long abase;
        if (windowed) {
            int b = mg / T_STEPS;
            int t = mg - b * T_STEPS;
            abase = ((long)(b * LL + t + shift)) * DD;
        } else {
            abase = (long)mg * lda;
        }
        aoff[it] = abase + koct * 8;
        boff[it] = (long)(n0 + r) * K + koct * 8;
    }

    const int wave = tid >> 6, lane = tid & 63;
    const int wr = (wave >> 1) * 64;
    const int wc = (wave & 1) * 64;
    const int q = lane >> 4, mm = lane & 15;

    f32x4 acc[4][4] = {};

    for (int k0 = 0; k0 < K; k0 += 32) {
        uint4 av[2], bv[2];
#pragma unroll
        for (int it = 0; it < 2; ++it) {
            av[it] = *(const uint4*)(A + aoff[it] + k0);
            bv[it] = *(const uint4*)(Bm + boff[it] + k0);
        }
        __syncthreads();
#pragma unroll
        for (int it = 0; it < 2; ++it) {
            int idx = it * 256 + tid;
            *(uint4*)((char*)Ash + idx * 16) = av[it];
            *(uint4*)((char*)Bsh + idx * 16) = bv[it];
        }
        __syncthreads();
        bf16x8 af[4], bfr[4];
#pragma unroll
        for (int i = 0; i < 4; ++i) {
            af[i]  = *(const bf16x8*)((char*)Ash + q * 2048 + (wr + i * 16 + mm) * 16);
            bfr[i] = *(const bf16x8*)((char*)Bsh + q * 2048 + (wc + i * 16 + mm) * 16);
        }
#pragma unroll
        for (int i = 0; i < 4; ++i)
#pragma unroll
            for (int j = 0; j < 4; ++j)
                acc[i][j] = __builtin_amdgcn_mfma_f32_16x16x32_bf16(af[i], bfr[j], acc[i][j], 0, 0, 0);
    }

#pragma unroll
    for (int i = 0; i < 4; ++i) {
        int rowb = m0 + wr + i * 16 + q * 4;
#pragma unroll
        for (int j = 0; j < 4; ++j) {
            int col = n0 + wc + j * 16 + mm;
            float bias = cbias ? cbias[col] : 0.0f;
#pragma unroll
            for (int r = 0; r < 4; ++r) {
                int gr = rowb + r;
                if (gr < M) {
                    float v = acc[i][j][r] + bias;
                    if (cmode == 0) ((float*)Cout)[(long)gr * ldc + col] = v;
                    else            ((bf16*)Cout)[(long)gr * ldc + col] = (bf16)v;
                }
            }
        }
    }
}

// ---------------------------------------------------------------------------
// vts_d[b,t] = dot(db[b,t,:], da[b,t,:]) -> joint cols 512..543 (hi/lo split + 1.0 + zeros)
// ---------------------------------------------------------------------------
__global__ void vts_kernel(const float* __restrict__ dbuf, const float* __restrict__ dabuf,
                           bf16* __restrict__ joint) {
    int gid = blockIdx.x * blockDim.x + threadIdx.x;
    int wid = gid >> 6, lane = gid & 63;
    if (wid >= MROWS) return;
    const float* p1 = dbuf + (long)wid * 512 + lane * 8;
    const float* p2 = dabuf + (long)wid * 512 + lane * 8;
    float s = 0.0f;
#pragma unroll
    for (int j = 0; j < 8; ++j) s += p1[j] * p2[j];
#pragma unroll
    for (int off = 32; off > 0; off >>= 1) s += __shfl_down(s, off);
    bf16* row = joint + (long)wid * 544;
    if (lane == 0) {
        bf16 hv = (bf16)s;
        float lo = s - (float)hv;
        row[512] = hv; row[513] = (bf16)lo; row[514] = hv; row[515] = (bf16)1.0f;
    }
    if (lane >= 4 && lane < 32) row[512 + lane] = (bf16)0.0f;  // cols 516..543
}

// ---------------------------------------------------------------------------
// Persistent LSTM: 128 blocks x 64 threads, PLAIN launch (co-resident: 128
// one-wave WGs on an idle 256-CU GPU; monotonic flags -> no deadlock).
// dir = blk>>6, each WG owns 8 hidden units; Whh A-fragments in VGPRs.
// hist layout per dir (u32-packed, PERMUTED hidden axis): [T+1][16 b][256 u32].
// position p <-> unit (p&~7)+((p&7)>>1)+4*(p&1); same permutation applied to
// Whh columns (k-invariant) and Wfc indexing.
//
// Coherence design (R5): ALL h/flag traffic is sc1 RELAXED atomics -> data
// lives at the coherence point; no stale cached copies can exist. Ordering
// needs exactly one `s_waitcnt vmcnt(0)` before the flag store (drain h
// stores) and program order on the reader. NO acquire/release fences: an
// agent-acquire in the spin loop emitted buffer_inv per poll from 128 WGs —
// an L2-invalidate storm that made R4 run at 10.6 us/step, 26 GB/s.
// ---------------------------------------------------------------------------
__global__ __launch_bounds__(64, 1)
void lstm_kernel(const float* __restrict__ Whh_fw, const float* __restrict__ Whh_bw,
                 const float* __restrict__ gih, u32* __restrict__ hist_fw,
                 u32* __restrict__ hist_bw, u32* __restrict__ flags) {
    const int wgid = blockIdx.x;
    const int dir = wgid >> 6;
    const int w = wgid & 63;
    const int j0 = w * 8;
    const int lane = threadIdx.x;
    const float* Whh = dir ? Whh_bw : Whh_fw;
    u32* hist = dir ? hist_bw : hist_fw;
    u32* fl = flags + dir * 64;

    const int q = lane >> 4, mm = lane & 15;

    // Pre-pack A fragments: local rows rl = u*4+g (u=unit, g=gate i/f/g/o),
    // MFMA A layout: lane holds A[m=lane&15][k=(lane>>4)*8 + j].
    // Column j of k-octet (ks,q): permuted position p=ks*32+q*8+j
    // -> Whh column (p&~7) + (j>>1) + 4*(j&1).
    bf16x8 afrag[2][16];
#pragma unroll
    for (int mt = 0; mt < 2; ++mt) {
        int rl = mt * 16 + mm;
        int u = rl >> 2, g = rl & 3;
        const float* wrow = Whh + ((long)(g * 512 + j0 + u)) * 512;
#pragma unroll
        for (int ks = 0; ks < 16; ++ks) {
            int base = ks * 32 + q * 8;
            bf16x8 f;
#pragma unroll
            for (int j = 0; j < 8; ++j) {
                int col = base + (j >> 1) + ((j & 1) << 2);
                f[j] = (bf16)wrow[col];
            }
            afrag[mt][ks] = f;
        }
    }

    float c0 = 0.0f, c1 = 0.0f;
    const int bcl = (mm < 8) ? mm : 0;  // clamp gih row for pad lanes
    for (int s = 0; s < T_STEPS; ++s) {
        const int t = dir ? (T_STEPS - 1 - s) : s;
        // B fragments from h slot s (relaxed sc1 u32 loads — data is at the
        // coherence point; first touch of this address by this CU).
        const u32* hrow = hist + (long)s * 4096 + mm * 256;
        bf16x8 bfrag[16];
#pragma unroll
        for (int ks = 0; ks < 16; ++ks) {
            int wbase = ks * 16 + q * 4;
            u32 wv[4];
#pragma unroll
            for (int i = 0; i < 4; ++i)
                wv[i] = __hip_atomic_load(hrow + wbase + i, __ATOMIC_RELAXED,
                                          __HIP_MEMORY_SCOPE_AGENT);
            bf16x8 f;
#pragma unroll
            for (int i = 0; i < 4; ++i) {
                f[2 * i]     = bits2bf(wv[i]);
                f[2 * i + 1] = bits2bf(wv[i] >> 16);
            }
            bfrag[ks] = f;
        }

        // C operand = precomputed input gates (bias included, (j*4+g) order)
        const float* gp = gih + ((long)(bcl * T_STEPS + t)) * 4096 + dir * 2048 + (j0 + q) * 4;
        f32x4 acc0 = *(const f32x4*)gp;
        f32x4 acc1 = *(const f32x4*)(gp + 16);
#pragma unroll
        for (int ks = 0; ks < 16; ++ks) {
            acc0 = __builtin_amdgcn_mfma_f32_16x16x32_bf16(afrag[0][ks], bfrag[ks], acc0, 0, 0, 0);
            acc1 = __builtin_amdgcn_mfma_f32_16x16x32_bf16(afrag[1][ks], bfrag[ks], acc1, 0, 0, 0);
        }
        // D layout: col=lane&15=b, row=(lane>>4)*4+reg -> unit q (+4), gate = reg
        float ig = sigm(acc0[0]), fg = sigm(acc0[1]), gg = tanh_f(acc0[2]), og = sigm(acc0[3]);
        c0 = fg * c0 + ig * gg;
        float h0 = og * tanh_f(c0);
        ig = sigm(acc1[0]); fg = sigm(acc1[1]); gg = tanh_f(acc1[2]); og = sigm(acc1[3]);
        c1 = fg * c1 + ig * gg;
        float h1 = og * tanh_f(c1);

        bool valid = (mm < 8);
        u32 pw = valid ? (bfbits(h0) | (bfbits(h1) << 16)) : 0u;
        __hip_atomic_store(hist + (long)(s + 1) * 4096 + mm * 256 + (j0 >> 1) + q, pw,
                           __ATOMIC_RELAXED, __HIP_MEMORY_SCOPE_AGENT);

        // Minimal release: drain the sc1 h stores, then publish the flag.
        asm volatile("s_waitcnt vmcnt(0)" ::: "memory");
        if (lane == 0)
            __hip_atomic_store(&fl[w], (u32)(s + 1), __ATOMIC_RELAXED,
                               __HIP_MEMORY_SCOPE_AGENT);
        const u32 tgt = (u32)(s + 1);
        while (true) {
            u32 v = __hip_atomic_load(&fl[lane], __ATOMIC_RELAXED,
                                      __HIP_MEMORY_SCOPE_AGENT);
            if (__all((int)(v >= tgt))) break;
        }
        asm volatile("" ::: "memory");  // compiler barrier: keep h loads after spin
    }
}

// ---------------------------------------------------------------------------
// out[b*T+t] = sigmoid(h_fw[t] . Wfc[:512] + h_bw[t] . Wfc[512:] + bfc)
// hist is u32-packed with the permuted hidden axis: lane reads words
// lane*4 .. +4: word i -> units 8*lane+i (lo16) and 8*lane+4+i (hi16).
// ---------------------------------------------------------------------------
__global__ void final_fc(const u32* __restrict__ hist_fw, const u32* __restrict__ hist_bw,
                         const float* __restrict__ Wfc, const float* __restrict__ bfc,
                         float* __restrict__ out) {
    int gid = blockIdx.x * blockDim.x + threadIdx.x;
    int wid = gid >> 6, lane = gid & 63;
    if (wid >= MROWS) return;
    int b = wid / T_STEPS, t = wid - b * T_STEPS;
    const u32* hf = hist_fw + (long)(t + 1) * 4096 + b * 256 + lane * 4;
    const u32* hb = hist_bw + (long)(T_STEPS - t) * 4096 + b * 256 + lane * 4;
    float s = 0.0f;
#pragma unroll
    for (int i = 0; i < 4; ++i) {
        u32 wf = hf[i], wb = hb[i];
        s += bits2f(wf) * Wfc[8 * lane + i] + bits2f(wf >> 16) * Wfc[8 * lane + 4 + i];
        s += bits2f(wb) * Wfc[512 + 8 * lane + i] + bits2f(wb >> 16) * Wfc[512 + 8 * lane + 4 + i];
    }
#pragma unroll
    for (int off = 32; off > 0; off >>= 1) s += __shfl_down(s, off);
    if (lane == 0) out[wid] = 1.0f / (1.0f + __expf(-(s + bfc[0])));
}

// ---------------------------------------------------------------------------

extern "C" void kernel_launch(void* const* d_in, const int* in_sizes, int n_in,
                              void* d_out, int out_size, void* d_ws, size_t ws_size,
                              hipStream_t stream) {
    const float* x      = (const float*)d_in[0];
    const float* Wdb    = (const float*)d_in[1];
    const float* bdb    = (const float*)d_in[2];
    const float* Wda    = (const float*)d_in[3];
    const float* bda    = (const float*)d_in[4];
    const float* Wr     = (const float*)d_in[5];
    const float* br     = (const float*)d_in[6];
    const float* Wih_fw = (const float*)d_in[7];
    const float* Whh_fw = (const float*)d_in[8];
    const float* bih_fw = (const float*)d_in[9];
    const float* bhh_fw = (const float*)d_in[10];
    const float* Wih_bw = (const float*)d_in[11];
    const float* Whh_bw = (const float*)d_in[12];
    const float* bih_bw = (const float*)d_in[13];
    const float* bhh_bw = (const float*)d_in[14];
    const float* Wfc    = (const float*)d_in[15];
    const float* bfc    = (const float*)d_in[16];
    float* out = (float*)d_out;

    // ---- workspace layout with aliasing (peak ~179.5 MB) ----
    char* p = (char*)d_ws;
    auto alloc = [&](size_t bytes) { char* r = p; p += (bytes + 255) & ~(size_t)255; return r; };
    // persistent region (~46.6 MB): alive until the end
    bf16* Wihc    = (bf16*)alloc((size_t)4096 * 544 * 2);            // 4.5 MB
    bf16* joint   = (bf16*)alloc((size_t)MROWS * 544 * 2);           // 8.8 MB
    u32* hist_fw  = (u32*)alloc((size_t)(T_STEPS + 1) * 4096 * 4);   // 16.6 MB
    u32* hist_bw  = (u32*)alloc((size_t)(T_STEPS + 1) * 4096 * 4);   // 16.6 MB
    u32* flags    = (u32*)alloc(512);
    // overlay region Q: phase-1 conv buffers, later overwritten by gih
    char* q0 = p;
    bf16* xb      = (bf16*)alloc((size_t)BB * LL * DD * 2);          // 33.6 MB
    bf16* Bdb     = (bf16*)alloc((size_t)512 * 10240 * 2);           // 10.5 MB
    bf16* Bda     = (bf16*)alloc((size_t)512 * 10240 * 2);           // 10.5 MB
    bf16* Br      = (bf16*)alloc((size_t)512 * 20480 * 2);           // 21.0 MB
    float* dbuf   = (float*)alloc((size_t)MROWS * 512 * 4);          // 16.6 MB
    float* dabuf  = (float*)alloc((size_t)MROWS * 512 * 4);          // 16.6 MB
    float* gih    = (float*)q0;  // 132.9 MB, overwrites all of the above
    (void)ws_size;

    cast_x_kernel<<<16384, 256, 0, stream>>>(x, xb, BB * LL * DD / 4);
    prep_convw<<<4096, 256, 0, stream>>>(Wdb, Wda, Wr, Bdb, Bda, Br);
    prep_wihc<<<4096, 256, 0, stream>>>(Wih_fw, bih_fw, bhh_fw, Wih_bw, bih_bw, bhh_bw, Wihc);
    init_kernel<<<16, 256, 0, stream>>>(hist_fw, hist_bw, flags);

    dim3 g1(64, 4);
    // db: window [t, t+5);  da: window [t+5, t+10);  r: window [t, t+10)
    gemm_bt<<<g1, 256, 0, stream>>>(xb, Bdb, dbuf, bdb, MROWS, 10240, 1, 0, 0, 512, 0);
    gemm_bt<<<g1, 256, 0, stream>>>(xb, Bda, dabuf, bda, MROWS, 10240, 1, 5, 0, 512, 0);
    gemm_bt<<<g1, 256, 0, stream>>>(xb, Br, joint, br, MROWS, 20480, 1, 0, 0, 544, 1);
    vts_kernel<<<(MROWS * 64 + 255) / 256, 256, 0, stream>>>(dbuf, dabuf, joint);

    // gih GEMM: reads only joint + Wihc; writes gih over the dead conv buffers
    dim3 g2(64, 32);
    gemm_bt<<<g2, 256, 0, stream>>>(joint, Wihc, gih, nullptr, MROWS, 544, 0, 0, 544, 4096, 0);

    lstm_kernel<<<dim3(128), dim3(64), 0, stream>>>(Whh_fw, Whh_bw, gih,
                                                    hist_fw, hist_bw, flags);

    final_fc<<<(MROWS * 64 + 255) / 256, 256, 0, stream>>>(hist_fw, hist_bw, Wfc, bfc, out);
}

// Round 6
// 6641.117 us; speedup vs baseline: 2.0230x; 1.2179x over previous
//
#include <hip/hip_runtime.h>

// Problem constants (reference: B=8, L=1024, D=2048, H=512, OMEGA=5)
#define BB 8
#define LL 1024
#define DD 2048
#define HHH 512
#define OM 5
#define T_STEPS 1014            // L - 2*OMEGA
#define MROWS (BB * T_STEPS)    // 8112
#define SENT 0xFFFFFFFFu        // bf16 NaN|NaN — unreachable for finite h

typedef __bf16 bf16;
typedef bf16 bf16x8 __attribute__((ext_vector_type(8)));
typedef bf16 bf16x4 __attribute__((ext_vector_type(4)));
typedef float f32x4 __attribute__((ext_vector_type(4)));
typedef unsigned int u32;

__device__ __forceinline__ float sigm(float x) { return 1.0f / (1.0f + __expf(-x)); }
__device__ __forceinline__ float tanh_f(float x) { return 2.0f / (1.0f + __expf(-2.0f * x)) - 1.0f; }
__device__ __forceinline__ u32 bfbits(float x) {
    bf16 b = (bf16)x;
    unsigned short s = __builtin_bit_cast(unsigned short, b);
    return (u32)s;
}
__device__ __forceinline__ float bits2f(u32 v) {
    unsigned short s = (unsigned short)(v & 0xffffu);
    return (float)__builtin_bit_cast(bf16, s);
}

#if defined(__has_builtin)
#if __has_builtin(__builtin_amdgcn_global_load_lds)
#define HAS_GLL 1
#endif
#endif
#ifndef HAS_GLL
#define HAS_GLL 0
#endif

#if HAS_GLL
__device__ __forceinline__ void llds16(const bf16* g, bf16* l) {
    __builtin_amdgcn_global_load_lds((const __attribute__((address_space(1))) void*)g,
                                     (__attribute__((address_space(3))) void*)l, 16, 0, 0);
}
#endif

// ---------------------------------------------------------------------------
// Prep kernels
// ---------------------------------------------------------------------------

__global__ void cast_x_kernel(const float* __restrict__ x, bf16* __restrict__ xb, int n4) {
    int i = blockIdx.x * 256 + threadIdx.x;
    if (i >= n4) return;
    float4 v = ((const float4*)x)[i];
    bf16x4 w = { (bf16)v.x, (bf16)v.y, (bf16)v.z, (bf16)v.w };
    *(bf16x4*)(xb + (long)i * 4) = w;
}

// Wdb/Wda: [H][D][5], Wr: [H][D][10]  ->  B^T layouts [H][K] with k = s*D + d
__global__ void prep_convw(const float* __restrict__ Wdb, const float* __restrict__ Wda,
                           const float* __restrict__ Wr,
                           bf16* __restrict__ Bdb, bf16* __restrict__ Bda, bf16* __restrict__ Br) {
    int idx = blockIdx.x * 256 + threadIdx.x;  // h*2048 + d
    if (idx >= HHH * DD) return;
    int h = idx >> 11, d = idx & 2047;
#pragma unroll
    for (int s = 0; s < 5; ++s) {
        Bdb[(long)h * 10240 + s * DD + d] = (bf16)Wdb[(long)(h * DD + d) * 5 + s];
        Bda[(long)h * 10240 + s * DD + d] = (bf16)Wda[(long)(h * DD + d) * 5 + s];
    }
#pragma unroll
    for (int s = 0; s < 10; ++s) {
        Br[(long)h * 20480 + s * DD + d] = (bf16)Wr[(long)(h * DD + d) * 10 + s];
    }
}

// Wihc: [4096][544]; output col c = dir*2048 + j*4 + g  <- Wih_dir row (g*512+j).
// K rows: 0..511 = Wih[:, :512]; 512 = hi(w512); 513 = hi(w512) (x vts_lo);
// 514 = lo(w512) (x vts_hi); 515 = bias (x 1.0); 516..543 = 0.
__global__ void prep_wihc(const float* __restrict__ Wih_fw, const float* __restrict__ bih_fw,
                          const float* __restrict__ bhh_fw,
                          const float* __restrict__ Wih_bw, const float* __restrict__ bih_bw,
                          const float* __restrict__ bhh_bw, bf16* __restrict__ Wihc) {
    int c = blockIdx.x;
    int tid = threadIdx.x;
    int dir = c >> 11;
    int jg = c & 2047;
    int j = jg >> 2, g = jg & 3;
    int row = g * 512 + j;
    const float* Wih = dir ? Wih_bw : Wih_fw;
    bf16* o = Wihc + (long)c * 544;
    for (int k = tid; k < 512; k += 256) o[k] = (bf16)Wih[(long)row * 513 + k];
    if (tid == 0) {
        float bias = dir ? (bih_bw[row] + bhh_bw[row]) : (bih_fw[row] + bhh_fw[row]);
        float w512 = Wih[(long)row * 513 + 512];
        bf16 hw = (bf16)w512;
        float lw = w512 - (float)hw;
        o[512] = hw; o[513] = hw; o[514] = (bf16)lw; o[515] = (bf16)bias;
    }
    if (tid >= 4 && tid < 32) o[512 + tid] = (bf16)0.0f;  // cols 516..543
}

// hist init: slot 0 = zeros (h_init), slots 1..T = SENT (un-written marker).
// Runs every call (harness re-poisons d_ws with 0xAA).
__global__ void init_kernel(u32* __restrict__ hf, u32* __restrict__ hb) {
    const long n4 = (long)(T_STEPS + 1) * 1024;  // uint4 count per dir
    long i = (long)blockIdx.x * 256 + threadIdx.x;
    if (i >= 2 * n4) return;
    u32* base = (i < n4) ? hf : hb;
    long k = (i < n4) ? i : (i - n4);
    u32 v = (k < 1024) ? 0u : SENT;  // first 1024 uint4 = slot 0
    uint4 val; val.x = v; val.y = v; val.z = v; val.w = v;
    ((uint4*)base)[k] = val;
}

// ---------------------------------------------------------------------------
// GEMM: C[M][*] = A_win/A_plain (bf16) @ B^T rows (bf16), fp32 accumulate.
// windowed: A row (b,t) = xb + (b*LL + t + shift)*DD  (contiguous im2col-free)
// cmode 0: fp32 store; cmode 1: bf16 store. cbias: per-output-col fp32 bias.
// Staging via global_load_lds width=16 (m97 pattern) when available.
// ---------------------------------------------------------------------------
__global__ __launch_bounds__(256, 2)
void gemm_bt(const bf16* __restrict__ A, const bf16* __restrict__ Bm, void* __restrict__ Cout,
             const float* __restrict__ cbias, int M, int K, int windowed, int shift,
             int lda, int ldc, int cmode) {
    __shared__ bf16 Ash[128 * 32];  // layout [koct][row][8]
    __shared__ bf16 Bsh[128 * 32];
    const int tid = threadIdx.x;
    const int m0 = blockIdx.x * 128;
    const int n0 = blockIdx.y * 128;

    long aoff[2], boff[2];
#pragma unroll
    for (int it = 0; it < 2; ++it) {
        int idx = it * 256 + tid;
        int r = idx & 127, koct = idx >> 7;
        int mg = m0 + r; if (mg >= M) mg = M - 1;
        long abase;
        if (windowed) {
            int b = mg / T_STEPS;
            int t = mg - b * T_STEPS;
            abase = ((long)(b * LL + t + shift)) * DD;
        } else {
            abase = (long)mg * lda;
        }
        aoff[it] = abase + koct * 8;
        boff[it] = (long)(n0 + r) * K + koct * 8;
    }

    const int wave = tid >> 6, lane = tid & 63;
    const int wr = (wave >> 1) * 64;
    const int wc = (wave & 1) * 64;
    const int q = lane >> 4, mm = lane & 15;

    f32x4 acc[4][4] = {};

    for (int k0 = 0; k0 < K; k0 += 32) {
#if HAS_GLL
        __syncthreads();  // protect LDS from overwrite while prior reads active
#pragma unroll
        for (int it = 0; it < 2; ++it) {
            // dst: lane writes (it*256 + wave*64 + lane)*16 bytes (HW: base+lane*16)
            bf16* la = Ash + (size_t)(it * 256 + wave * 64) * 8;
            bf16* lb = Bsh + (size_t)(it * 256 + wave * 64) * 8;
            llds16(A + aoff[it] + k0, la);
            llds16(Bm + boff[it] + k0, lb);
        }
        __syncthreads();  // compiler drains vmcnt(0) before barrier -> LDS ready
#else
        uint4 av[2], bv[2];
#pragma unroll
        for (int it = 0; it < 2; ++it) {
            av[it] = *(const uint4*)(A + aoff[it] + k0);
            bv[it] = *(const uint4*)(Bm + boff[it] + k0);
        }
        __syncthreads();
#pragma unroll
        for (int it = 0; it < 2; ++it) {
            int idx = it * 256 + tid;
            *(uint4*)((char*)Ash + idx * 16) = av[it];
            *(uint4*)((char*)Bsh + idx * 16) = bv[it];
        }
        __syncthreads();
#endif
        bf16x8 af[4], bfr[4];
#pragma unroll
        for (int i = 0; i < 4; ++i) {
            af[i]  = *(const bf16x8*)((char*)Ash + q * 2048 + (wr + i * 16 + mm) * 16);
            bfr[i] = *(const bf16x8*)((char*)Bsh + q * 2048 + (wc + i * 16 + mm) * 16);
        }
#pragma unroll
        for (int i = 0; i < 4; ++i)
#pragma unroll
            for (int j = 0; j < 4; ++j)
                acc[i][j] = __builtin_amdgcn_mfma_f32_16x16x32_bf16(af[i], bfr[j], acc[i][j], 0, 0, 0);
    }

#pragma unroll
    for (int i = 0; i < 4; ++i) {
        int rowb = m0 + wr + i * 16 + q * 4;
#pragma unroll
        for (int j = 0; j < 4; ++j) {
            int col = n0 + wc + j * 16 + mm;
            float bias = cbias ? cbias[col] : 0.0f;
#pragma unroll
            for (int r = 0; r < 4; ++r) {
                int gr = rowb + r;
                if (gr < M) {
                    float v = acc[i][j][r] + bias;
                    if (cmode == 0) ((float*)Cout)[(long)gr * ldc + col] = v;
                    else            ((bf16*)Cout)[(long)gr * ldc + col] = (bf16)v;
                }
            }
        }
    }
}

// ---------------------------------------------------------------------------
// vts_d[b,t] = dot(db[b,t,:], da[b,t,:]) -> joint cols 512..543 (hi/lo split + 1.0 + zeros)
// ---------------------------------------------------------------------------
__global__ void vts_kernel(const float* __restrict__ dbuf, const float* __restrict__ dabuf,
                           bf16* __restrict__ joint) {
    int gid = blockIdx.x * blockDim.x + threadIdx.x;
    int wid = gid >> 6, lane = gid & 63;
    if (wid >= MROWS) return;
    const float* p1 = dbuf + (long)wid * 512 + lane * 8;
    const float* p2 = dabuf + (long)wid * 512 + lane * 8;
    float s = 0.0f;
#pragma unroll
    for (int j = 0; j < 8; ++j) s += p1[j] * p2[j];
#pragma unroll
    for (int off = 32; off > 0; off >>= 1) s += __shfl_down(s, off);
    bf16* row = joint + (long)wid * 544;
    if (lane == 0) {
        bf16 hv = (bf16)s;
        float lo = s - (float)hv;
        row[512] = hv; row[513] = (bf16)lo; row[514] = hv; row[515] = (bf16)1.0f;
    }
    if (lane >= 4 && lane < 32) row[512 + lane] = (bf16)0.0f;  // cols 516..543
}

// ---------------------------------------------------------------------------
// Persistent LSTM: 128 blocks x 64 threads, plain launch (128 one-wave WGs on
// an idle 256-CU GPU => co-resident; dataflow sync can't deadlock: monotone).
//
// SENTINEL DATAFLOW SYNC (R6): no flags, no fences. Slots 1..T pre-filled
// with 0xFFFFFFFF (bf16 NaN pair — finite h never produces it). Writers
// publish h via relaxed sc1 u32 stores; readers poll the h words themselves
// (u32 load is single-copy atomic, no tearing) until all 64 != SENT.
// One IC round trip replaces R5's store->vmcnt(0)->flag->poll->load chain.
// hist layout per dir (u32-packed, PERMUTED hidden axis): [T+1][16 b][256 u32].
// position p <-> unit (p&~7)+((p&7)>>1)+4*(p&1); same perm on Whh cols & Wfc.
// ---------------------------------------------------------------------------
__global__ __launch_bounds__(64, 1)
void lstm_kernel(const float* __restrict__ Whh_fw, const float* __restrict__ Whh_bw,
                 const float* __restrict__ gih, u32* __restrict__ hist_fw,
                 u32* __restrict__ hist_bw) {
    const int wgid = blockIdx.x;
    const int dir = wgid >> 6;
    const int w = wgid & 63;
    const int j0 = w * 8;
    const int lane = threadIdx.x;
    const float* Whh = dir ? Whh_bw : Whh_fw;
    u32* hist = dir ? hist_bw : hist_fw;

    const int q = lane >> 4, mm = lane & 15;

    // Pre-pack A fragments: local rows rl = u*4+g (u=unit, g=gate i/f/g/o),
    // MFMA A layout: lane holds A[m=lane&15][k=(lane>>4)*8 + j].
    // Column j of k-octet (ks,q): permuted position p=ks*32+q*8+j
    // -> Whh column (p&~7) + (j>>1) + 4*(j&1).
    bf16x8 afrag[2][16];
#pragma unroll
    for (int mt = 0; mt < 2; ++mt) {
        int rl = mt * 16 + mm;
        int u = rl >> 2, g = rl & 3;
        const float* wrow = Whh + ((long)(g * 512 + j0 + u)) * 512;
#pragma unroll
        for (int ks = 0; ks < 16; ++ks) {
            int base = ks * 32 + q * 8;
            bf16x8 f;
#pragma unroll
            for (int j = 0; j < 8; ++j) {
                int col = base + (j >> 1) + ((j & 1) << 2);
                f[j] = (bf16)wrow[col];
            }
            afrag[mt][ks] = f;
        }
    }

    float c0 = 0.0f, c1 = 0.0f;
    const int bcl = (mm < 8) ? mm : 0;  // clamp gih row for pad lanes

    // prefetch gih for s=0
    {
        int t0 = dir ? (T_STEPS - 1) : 0;
        const float* gp = gih + ((long)(bcl * T_STEPS + t0)) * 4096 + dir * 2048 + (j0 + q) * 4;
        // loaded below via pg0/pg1 initialization
    }
    int tcur = dir ? (T_STEPS - 1) : 0;
    const float* gp0 = gih + ((long)(bcl * T_STEPS + tcur)) * 4096 + dir * 2048 + (j0 + q) * 4;
    f32x4 pg0 = *(const f32x4*)gp0;
    f32x4 pg1 = *(const f32x4*)(gp0 + 16);

    for (int s = 0; s < T_STEPS; ++s) {
        // --- poll-load B fragments from h slot s (data IS the sync) ---
        const u32* hrow = hist + (long)s * 4096 + mm * 256;
        uint4 wv[16];
        for (;;) {
#pragma unroll
            for (int ks = 0; ks < 16; ++ks) {
                const u32* pp = hrow + ks * 16 + q * 4;
                wv[ks].x = __hip_atomic_load(pp + 0, __ATOMIC_RELAXED, __HIP_MEMORY_SCOPE_AGENT);
                wv[ks].y = __hip_atomic_load(pp + 1, __ATOMIC_RELAXED, __HIP_MEMORY_SCOPE_AGENT);
                wv[ks].z = __hip_atomic_load(pp + 2, __ATOMIC_RELAXED, __HIP_MEMORY_SCOPE_AGENT);
                wv[ks].w = __hip_atomic_load(pp + 3, __ATOMIC_RELAXED, __HIP_MEMORY_SCOPE_AGENT);
            }
            u32 ok = 1u;
#pragma unroll
            for (int ks = 0; ks < 16; ++ks) {
                ok &= (wv[ks].x != SENT) ? 1u : 0u;
                ok &= (wv[ks].y != SENT) ? 1u : 0u;
                ok &= (wv[ks].z != SENT) ? 1u : 0u;
                ok &= (wv[ks].w != SENT) ? 1u : 0u;
            }
            if (__all((int)ok)) break;
            __builtin_amdgcn_s_sleep(1);
        }
        bf16x8 bfrag[16];
#pragma unroll
        for (int ks = 0; ks < 16; ++ks) bfrag[ks] = __builtin_bit_cast(bf16x8, wv[ks]);

        // C operand = precomputed input gates (bias included, (j*4+g) order)
        f32x4 acc0 = pg0, acc1 = pg1;
        f32x4 acc0b = {0.0f, 0.0f, 0.0f, 0.0f}, acc1b = {0.0f, 0.0f, 0.0f, 0.0f};

        // prefetch gih for next step (hides under the MFMA chain)
        if (s + 1 < T_STEPS) {
            int tn = dir ? (T_STEPS - 2 - s) : (s + 1);
            const float* gpn = gih + ((long)(bcl * T_STEPS + tn)) * 4096 + dir * 2048 + (j0 + q) * 4;
            pg0 = *(const f32x4*)gpn;
            pg1 = *(const f32x4*)(gpn + 16);
        }

#pragma unroll
        for (int ks = 0; ks < 8; ++ks) {
            acc0  = __builtin_amdgcn_mfma_f32_16x16x32_bf16(afrag[0][ks],     bfrag[ks],     acc0,  0, 0, 0);
            acc1  = __builtin_amdgcn_mfma_f32_16x16x32_bf16(afrag[1][ks],     bfrag[ks],     acc1,  0, 0, 0);
            acc0b = __builtin_amdgcn_mfma_f32_16x16x32_bf16(afrag[0][ks + 8], bfrag[ks + 8], acc0b, 0, 0, 0);
            acc1b = __builtin_amdgcn_mfma_f32_16x16x32_bf16(afrag[1][ks + 8], bfrag[ks + 8], acc1b, 0, 0, 0);
        }
        acc0 += acc0b;
        acc1 += acc1b;

        // D layout: col=lane&15=b, row=(lane>>4)*4+reg -> unit q (+4), gate = reg
        float ig = sigm(acc0[0]), fg = sigm(acc0[1]), gg = tanh_f(acc0[2]), og = sigm(acc0[3]);
        c0 = fg * c0 + ig * gg;
        float h0 = og * tanh_f(c0);
        ig = sigm(acc1[0]); fg = sigm(acc1[1]); gg = tanh_f(acc1[2]); og = sigm(acc1[3]);
        c1 = fg * c1 + ig * gg;
        float h1 = og * tanh_f(c1);

        bool valid = (mm < 8);
        u32 pw = valid ? (bfbits(h0) | (bfbits(h1) << 16)) : 0u;
        __hip_atomic_store(hist + (long)(s + 1) * 4096 + mm * 256 + (j0 >> 1) + q, pw,
                           __ATOMIC_RELAXED, __HIP_MEMORY_SCOPE_AGENT);
    }
}

// ---------------------------------------------------------------------------
// out[b*T+t] = sigmoid(h_fw[t] . Wfc[:512] + h_bw[t] . Wfc[512:] + bfc)
// hist is u32-packed with the permuted hidden axis: lane reads words
// lane*4 .. +4: word i -> units 8*lane+i (lo16) and 8*lane+4+i (hi16).
// ---------------------------------------------------------------------------
__global__ void final_fc(const u32* __restrict__ hist_fw, const u32* __restrict__ hist_bw,
                         const float* __restrict__ Wfc, const float* __restrict__ bfc,
                         float* __restrict__ out) {
    int gid = blockIdx.x * blockDim.x + threadIdx.x;
    int wid = gid >> 6, lane = gid & 63;
    if (wid >= MROWS) return;
    int b = wid / T_STEPS, t = wid - b * T_STEPS;
    const u32* hf = hist_fw + (long)(t + 1) * 4096 + b * 256 + lane * 4;
    const u32* hb = hist_bw + (long)(T_STEPS - t) * 4096 + b * 256 + lane * 4;
    float s = 0.0f;
#pragma unroll
    for (int i = 0; i < 4; ++i) {
        u32 wf = hf[i], wb = hb[i];
        s += bits2f(wf) * Wfc[8 * lane + i] + bits2f(wf >> 16) * Wfc[8 * lane + 4 + i];
        s += bits2f(wb) * Wfc[512 + 8 * lane + i] + bits2f(wb >> 16) * Wfc[512 + 8 * lane + 4 + i];
    }
#pragma unroll
    for (int off = 32; off > 0; off >>= 1) s += __shfl_down(s, off);
    if (lane == 0) out[wid] = 1.0f / (1.0f + __expf(-(s + bfc[0])));
}

// ---------------------------------------------------------------------------

extern "C" void kernel_launch(void* const* d_in, const int* in_sizes, int n_in,
                              void* d_out, int out_size, void* d_ws, size_t ws_size,
                              hipStream_t stream) {
    const float* x      = (const float*)d_in[0];
    const float* Wdb    = (const float*)d_in[1];
    const float* bdb    = (const float*)d_in[2];
    const float* Wda    = (const float*)d_in[3];
    const float* bda    = (const float*)d_in[4];
    const float* Wr     = (const float*)d_in[5];
    const float* br     = (const float*)d_in[6];
    const float* Wih_fw = (const float*)d_in[7];
    const float* Whh_fw = (const float*)d_in[8];
    const float* bih_fw = (const float*)d_in[9];
    const float* bhh_fw = (const float*)d_in[10];
    const float* Wih_bw = (const float*)d_in[11];
    const float* Whh_bw = (const float*)d_in[12];
    const float* bih_bw = (const float*)d_in[13];
    const float* bhh_bw = (const float*)d_in[14];
    const float* Wfc    = (const float*)d_in[15];
    const float* bfc    = (const float*)d_in[16];
    float* out = (float*)d_out;

    // ---- workspace layout with aliasing (peak ~179.5 MB) ----
    char* p = (char*)d_ws;
    auto alloc = [&](size_t bytes) { char* r = p; p += (bytes + 255) & ~(size_t)255; return r; };
    // persistent region (~46.6 MB): alive until the end
    bf16* Wihc    = (bf16*)alloc((size_t)4096 * 544 * 2);            // 4.5 MB
    bf16* joint   = (bf16*)alloc((size_t)MROWS * 544 * 2);           // 8.8 MB
    u32* hist_fw  = (u32*)alloc((size_t)(T_STEPS + 1) * 4096 * 4);   // 16.6 MB
    u32* hist_bw  = (u32*)alloc((size_t)(T_STEPS + 1) * 4096 * 4);   // 16.6 MB
    // overlay region Q: phase-1 conv buffers, later overwritten by gih
    char* q0 = p;
    bf16* xb      = (bf16*)alloc((size_t)BB * LL * DD * 2);          // 33.6 MB
    bf16* Bdb     = (bf16*)alloc((size_t)512 * 10240 * 2);           // 10.5 MB
    bf16* Bda     = (bf16*)alloc((size_t)512 * 10240 * 2);           // 10.5 MB
    bf16* Br      = (bf16*)alloc((size_t)512 * 20480 * 2);           // 21.0 MB
    float* dbuf   = (float*)alloc((size_t)MROWS * 512 * 4);          // 16.6 MB
    float* dabuf  = (float*)alloc((size_t)MROWS * 512 * 4);          // 16.6 MB
    float* gih    = (float*)q0;  // 132.9 MB, overwrites all of the above
    (void)ws_size;

    cast_x_kernel<<<16384, 256, 0, stream>>>(x, xb, BB * LL * DD / 4);
    prep_convw<<<4096, 256, 0, stream>>>(Wdb, Wda, Wr, Bdb, Bda, Br);
    prep_wihc<<<4096, 256, 0, stream>>>(Wih_fw, bih_fw, bhh_fw, Wih_bw, bih_bw, bhh_bw, Wihc);
    {
        long n4 = (long)(T_STEPS + 1) * 1024 * 2;
        init_kernel<<<(int)((n4 + 255) / 256), 256, 0, stream>>>(hist_fw, hist_bw);
    }

    dim3 g1(64, 4);
    // db: window [t, t+5);  da: window [t+5, t+10);  r: window [t, t+10)
    gemm_bt<<<g1, 256, 0, stream>>>(xb, Bdb, dbuf, bdb, MROWS, 10240, 1, 0, 0, 512, 0);
    gemm_bt<<<g1, 256, 0, stream>>>(xb, Bda, dabuf, bda, MROWS, 10240, 1, 5, 0, 512, 0);
    gemm_bt<<<g1, 256, 0, stream>>>(xb, Br, joint, br, MROWS, 20480, 1, 0, 0, 544, 1);
    vts_kernel<<<(MROWS * 64 + 255) / 256, 256, 0, stream>>>(dbuf, dabuf, joint);

    // gih GEMM: reads only joint + Wihc; writes gih over the dead conv buffers
    dim3 g2(64, 32);
    gemm_bt<<<g2, 256, 0, stream>>>(joint, Wihc, gih, nullptr, MROWS, 544, 0, 0, 544, 4096, 0);

    lstm_kernel<<<dim3(128), dim3(64), 0, stream>>>(Whh_fw, Whh_bw, gih, hist_fw, hist_bw);

    final_fc<<<(MROWS * 64 + 255) / 256, 256, 0, stream>>>(hist_fw, hist_bw, Wfc, bfc, out);
}